// Round 13
// baseline (85.176 us; speedup 1.0000x reference)
//
#include <hip/hip_runtime.h>
#include <hip/hip_bf16.h>
#include <math.h>

#define TT 1024
#define NTYPE 16
#define NNODE 256
#define KCAP 512   // compacted masked rows per batch (expected ~192; 26 sigma headroom)

// ws layout (bytes):
//   0        : cnt[64] int
//   1024     : slotmap[64][1024] short          128 KB
//   132096   : part[4096][8] f32                128 KB
//   265216   : dpart[64][10] f32                2.5 KB
//   1048576  : ma [64][KCAP][256] f16           16 MB
//   +16M     : pb [64][KCAP][256] f16           16 MB
#define SLOT_OFF  1024
#define PART_OFF  132096
#define DPART_OFF 265216
#define MA_OFF    1048576ll
#define PB_OFF    (MA_OFF + 64ll*KCAP*256*2)

typedef __fp16 h2 __attribute__((ext_vector_type(2)));
typedef __fp16 h4 __attribute__((ext_vector_type(4)));
typedef float  f4v __attribute__((ext_vector_type(4)));

__device__ __forceinline__ float wsum(float v) {
    for (int o = 32; o > 0; o >>= 1) v += __shfl_xor(v, o);
    return v;
}
// DPP butterfly adds (VALU pipe, no LDS)
template<int CTRL>
__device__ __forceinline__ float dppadd(float v) {
    int p = __builtin_amdgcn_update_dpp(0, __float_as_int(v), CTRL, 0xF, 0xF, true);
    return v + __int_as_float(p);
}
__device__ __forceinline__ float gsum16(float v) {
    v = dppadd<0xB1>(v);    // quad_perm [1,0,3,2]
    v = dppadd<0x4E>(v);    // quad_perm [2,3,0,1]
    v = dppadd<0x141>(v);   // row_half_mirror
    v = dppadd<0x140>(v);   // row_mirror
    return v;
}
__device__ __forceinline__ unsigned pkh(float x, float y) {  // pack 2 f32 -> 2 f16
    h2 r = __builtin_amdgcn_cvt_pkrtz(x, y);
    union { h2 h; unsigned u; } c; c.h = r; return c.u;
}
__device__ __forceinline__ float fdot2(h2 a, h2 b, float c) {
#if __has_builtin(__builtin_amdgcn_fdot2)
    return __builtin_amdgcn_fdot2(a, b, c, false);
#else
    return c + (float)a[0] * (float)b[0] + (float)a[1] * (float)b[1];
#endif
}
__device__ __forceinline__ float4 ntload4(const float* p) {
    f4v v = __builtin_nontemporal_load((const f4v*)p);
    return make_float4(v.x, v.y, v.z, v.w);
}
__device__ __forceinline__ float sel4(float4 v, int e) {
    float x = (e & 1) ? v.y : v.x;
    float y = (e & 1) ? v.w : v.z;
    return (e & 2) ? y : x;
}
__device__ __forceinline__ float sel16(float4 v0, float4 v1, float4 v2, float4 v3,
                                       int j, int e) {
    float s0 = sel4(v0, e), s1 = sel4(v1, e), s2 = sel4(v2, e), s3 = sel4(v3, e);
    float c01 = (j & 1) ? s1 : s0;
    float c23 = (j & 1) ? s3 : s2;
    return (j & 2) ? c23 : c01;
}

// ---- deterministic compaction slots: per-batch prefix sum of the mask ----
__global__ __launch_bounds__(256) void scan_kernel(const float* __restrict__ seq,
                                                   int* __restrict__ cnt,
                                                   short* __restrict__ slotmap)
{
    const int b = blockIdx.x;
    const int tid = threadIdx.x;
    const int lane = tid & 63, w = tid >> 6;
    const int t0 = tid * 4;
    int m0 = 0, m1 = 0, m2 = 0, m3 = 0;
    {
        int tt;
        tt = (int)seq[((size_t)b * TT + t0 + 1) * 4];               m0 = (tt >= 3 && tt <= 5);
        tt = (int)seq[((size_t)b * TT + t0 + 2) * 4];               m1 = (tt >= 3 && tt <= 5);
        tt = (int)seq[((size_t)b * TT + t0 + 3) * 4];               m2 = (tt >= 3 && tt <= 5);
        if (t0 + 3 < TT - 1) {
            tt = (int)seq[((size_t)b * TT + t0 + 4) * 4];           m3 = (tt >= 3 && tt <= 5);
        }
    }
    int lc = m0 + m1 + m2 + m3;
    int inc = lc;
    for (int o = 1; o < 64; o <<= 1) {
        int v = __shfl_up(inc, o);
        if (lane >= o) inc += v;
    }
    __shared__ int wtot[4];
    if (lane == 63) wtot[w] = inc;
    __syncthreads();
    int woff = 0;
    for (int i = 0; i < 4; ++i) woff += (i < w) ? wtot[i] : 0;
    int run = woff + inc - lc;
    if (m0) { slotmap[(size_t)b * TT + t0 + 0] = (short)run; ++run; }
    if (m1) { slotmap[(size_t)b * TT + t0 + 1] = (short)run; ++run; }
    if (m2) { slotmap[(size_t)b * TT + t0 + 2] = (short)run; ++run; }
    if (m3) { slotmap[(size_t)b * TT + t0 + 3] = (short)run; ++run; }
    if (tid == 255) cnt[b] = woff + inc;
}

// ---- fused per-row stats: 16-lane group per row, 4 rows per wave ----
__global__ __launch_bounds__(256) void stats_kernel(
    const float* __restrict__ tl, const float* __restrict__ al,
    const float* __restrict__ bl, const float* __restrict__ vals,
    const float* __restrict__ seq, const short* __restrict__ slotmap,
    float* __restrict__ part,
    unsigned short* __restrict__ ma, unsigned short* __restrict__ pb)
{
    const int tid = threadIdx.x;
    const int w = tid >> 6, lane = tid & 63;
    const int s = lane & 15;                       // sublane within 16-lane group
    const int rowbase = blockIdx.x * 16 + w * 4;
    const int row = rowbase + (lane >> 4);
    const int b = row >> 10, t = row & 1023;

    // shifted target (group-uniform)
    float4 tgt = make_float4(0.f, 0.f, 0.f, 0.f);
    if (t < TT - 1) tgt = *(const float4*)(seq + (size_t)(row + 1) * 4);
    const int   t_type = (int)tgt.x;
    const int   t_a    = (int)tgt.y;
    const int   t_b    = (int)tgt.z;
    const float t_val  = tgt.w;
    const float mask   = (t_type >= 3 && t_type <= 5) ? 1.f : 0.f;

    // ---- type softmax: exactly 1 logit per sublane ----
    float tlv = tl[(size_t)rowbase * 16 + lane];
    float te  = __expf(tlv);
    float tsum = gsum16(te);
    float tcs  = gsum16((s >= 3 && s <= 5) ? te : 0.f);
    float p_comp = tcs / tsum;
    float ce_type = __logf(tsum) - __shfl(tlv, (lane & 48) + t_type);

    // ---- node a/b: 16 logits per sublane (4 x float4, stride-64 chunks) ----
    const float* arow = al + (size_t)row * 256;
    float4 a0 = ntload4(arow + s * 4);
    float4 a1 = ntload4(arow + s * 4 + 64);
    float4 a2 = ntload4(arow + s * 4 + 128);
    float4 a3 = ntload4(arow + s * 4 + 192);
    const float* brow = bl + (size_t)row * 256;
    float4 b0 = ntload4(brow + s * 4);
    float4 b1 = ntload4(brow + s * 4 + 64);
    float4 b2 = ntload4(brow + s * 4 + 128);
    float4 b3 = ntload4(brow + s * 4 + 192);

    // CE gathers on raw logits
    const int ja = t_a >> 6, sa = (t_a >> 2) & 15, ea = t_a & 3;
    const int jb = t_b >> 6, sb = (t_b >> 2) & 15, eb = t_b & 3;
    float ga = __shfl(sel16(a0, a1, a2, a3, ja, ea), (lane & 48) + sa);
    float gb = __shfl(sel16(b0, b1, b2, b3, jb, eb), (lane & 48) + sb);

    float ea0x = __expf(a0.x), ea0y = __expf(a0.y), ea0z = __expf(a0.z), ea0w = __expf(a0.w);
    float ea1x = __expf(a1.x), ea1y = __expf(a1.y), ea1z = __expf(a1.z), ea1w = __expf(a1.w);
    float ea2x = __expf(a2.x), ea2y = __expf(a2.y), ea2z = __expf(a2.z), ea2w = __expf(a2.w);
    float ea3x = __expf(a3.x), ea3y = __expf(a3.y), ea3z = __expf(a3.z), ea3w = __expf(a3.w);
    float eb0x = __expf(b0.x), eb0y = __expf(b0.y), eb0z = __expf(b0.z), eb0w = __expf(b0.w);
    float eb1x = __expf(b1.x), eb1y = __expf(b1.y), eb1z = __expf(b1.z), eb1w = __expf(b1.w);
    float eb2x = __expf(b2.x), eb2y = __expf(b2.y), eb2z = __expf(b2.z), eb2w = __expf(b2.w);
    float eb3x = __expf(b3.x), eb3y = __expf(b3.y), eb3z = __expf(b3.z), eb3w = __expf(b3.w);

    float lsa = ((ea0x + ea0y) + (ea0z + ea0w)) + ((ea1x + ea1y) + (ea1z + ea1w))
              + ((ea2x + ea2y) + (ea2z + ea2w)) + ((ea3x + ea3y) + (ea3z + ea3w));
    float lsb = ((eb0x + eb0y) + (eb0z + eb0w)) + ((eb1x + eb1y) + (eb1z + eb1w))
              + ((eb2x + eb2y) + (eb2z + eb2w)) + ((eb3x + eb3y) + (eb3z + eb3w));
    float asum = gsum16(lsa);
    float bsum = gsum16(lsb);
    float ainv = 1.f / asum, binv = 1.f / bsum;

    float ce_a = __logf(asum) - ga;
    float ce_b = __logf(bsum) - gb;

    // selfloop dot
    float dl = ((ea0x * eb0x + ea0y * eb0y) + (ea0z * eb0z + ea0w * eb0w))
             + ((ea1x * eb1x + ea1y * eb1y) + (ea1z * eb1z + ea1w * eb1w))
             + ((ea2x * eb2x + ea2y * eb2y) + (ea2z * eb2z + ea2w * eb2w))
             + ((ea3x * eb3x + ea3y * eb3y) + (ea3z * eb3z + ea3w * eb3w));
    float dot = gsum16(dl) * ainv * binv;

    // gnd: node cols 0,1 live on sublane 0 elements x,y
    float s0c = ((ea0x * ainv) + (eb0x * binv)) * p_comp;
    float s1c = ((ea0y * ainv) + (eb0y * binv)) * p_comp;

    float pv = vals[row];
    float vloss = mask * (pv - t_val) * (pv - t_val);

    // ---- compacted f16 prob rows ----
    if (mask > 0.f) {
        int slot = slotmap[row];
        if (slot < KCAP) {
            size_t base = ((size_t)b * KCAP + slot) * 256 + s * 4;
            *(uint2*)(ma + base)       = make_uint2(pkh(ea0x * ainv, ea0y * ainv), pkh(ea0z * ainv, ea0w * ainv));
            *(uint2*)(ma + base + 64)  = make_uint2(pkh(ea1x * ainv, ea1y * ainv), pkh(ea1z * ainv, ea1w * ainv));
            *(uint2*)(ma + base + 128) = make_uint2(pkh(ea2x * ainv, ea2y * ainv), pkh(ea2z * ainv, ea2w * ainv));
            *(uint2*)(ma + base + 192) = make_uint2(pkh(ea3x * ainv, ea3y * ainv), pkh(ea3z * ainv, ea3w * ainv));
            *(uint2*)(pb + base)       = make_uint2(pkh(eb0x * binv, eb0y * binv), pkh(eb0z * binv, eb0w * binv));
            *(uint2*)(pb + base + 64)  = make_uint2(pkh(eb1x * binv, eb1y * binv), pkh(eb1z * binv, eb1w * binv));
            *(uint2*)(pb + base + 128) = make_uint2(pkh(eb2x * binv, eb2y * binv), pkh(eb2z * binv, eb2w * binv));
            *(uint2*)(pb + base + 192) = make_uint2(pkh(eb3x * binv, eb3y * binv), pkh(eb3z * binv, eb3w * binv));
        }
    }

    // ---- reduce 8 scalars: group leaders, then xor16+xor32 across groups ----
    float r0 = (s == 0) ? ce_type       : 0.f;
    float r1 = (s == 0) ? mask          : 0.f;
    float r2 = (s == 0) ? mask * ce_a   : 0.f;
    float r3 = (s == 0) ? mask * ce_b   : 0.f;
    float r4 = (s == 0) ? vloss         : 0.f;
    float r5 = (s == 0) ? mask * dot    : 0.f;
    float r6 = (s == 0) ? s0c           : 0.f;
    float r7 = (s == 0) ? s1c           : 0.f;
#define XR(v) v += __shfl_xor(v, 16); v += __shfl_xor(v, 32);
    XR(r0) XR(r1) XR(r2) XR(r3) XR(r4) XR(r5) XR(r6) XR(r7)
#undef XR
    __shared__ float red[4][8];
    if (lane == 0) {
        red[w][0] = r0; red[w][1] = r1; red[w][2] = r2; red[w][3] = r3;
        red[w][4] = r4; red[w][5] = r5; red[w][6] = r6; red[w][7] = r7;
    }
    __syncthreads();
    if (tid < 8) {
        part[(size_t)blockIdx.x * 8 + tid] =
            red[0][tid] + red[1][tid] + red[2][tid] + red[3][tid];
    }
}

// ---- fused ec GEMM + dup penalty: 64x64 tile pairs, f16 dot2 (R7-proven layout) ----
// LDS per array: [8 kgroups][64 cols] of h4 (4 consecutive k per col),
// byte addr = (g*512 + col*8) ^ (((col>>3)&7)<<4)  -> conflict-free staging writes,
// <=2-way (free) compute reads, static LDS bases only.
__constant__ int cTI[10] = {0, 1, 2, 3, 0, 0, 0, 1, 1, 2};
__constant__ int cTJ[10] = {0, 1, 2, 3, 1, 2, 3, 2, 3, 3};

__global__ __launch_bounds__(256) void gemm_dup(
    const unsigned short* __restrict__ ma, const unsigned short* __restrict__ pb,
    const int* __restrict__ cnt, float* __restrict__ dpart)
{
    __shared__ char lds0[4096], lds1[4096], lds2[4096], lds3[4096];
    const int b = blockIdx.y;
    int K = cnt[b]; if (K > KCAP) K = KCAP;
    const int p = blockIdx.x;
    const int I0 = cTI[p] * 64, J0 = cTJ[p] * 64;
    const float wgt = (I0 == J0) ? 1.f : 2.f;
    const int tid = threadIdx.x;
    const int lr = tid >> 3, lc = (tid & 7) * 8;
    const int tx = tid & 15, ty = tid >> 4;
    const size_t bb = (size_t)b * KCAP * 256;
    float cIJ[4][4] = {};   // cIJ[r][c] = ec[I0+ty*4+r][J0+tx*4+c]
    float cJI[4][4] = {};   // cJI[r][c] = ec[J0+tx*4+c][I0+ty*4+r]

    for (int k0 = 0; k0 < K; k0 += 32) {
        const int kr = k0 + lr;
        uint4 vai = make_uint4(0,0,0,0), vbi = vai, vaj = vai, vbj = vai;
        if (kr < K) {
            size_t rb = bb + (size_t)kr * 256;
            vai = *(const uint4*)(ma + rb + I0 + lc);
            vbi = *(const uint4*)(pb + rb + I0 + lc);
            vaj = *(const uint4*)(ma + rb + J0 + lc);
            vbj = *(const uint4*)(pb + rb + J0 + lc);
        }
        __syncthreads();
        {
            const int g = lr >> 2;
            const int ko = (lr & 3) * 2;
            const __fp16* hai = (const __fp16*)&vai;
            const __fp16* hbi = (const __fp16*)&vbi;
            const __fp16* haj = (const __fp16*)&vaj;
            const __fp16* hbj = (const __fp16*)&vbj;
#pragma unroll
            for (int j = 0; j < 8; ++j) {
                const int col = lc + j;
                const int off = ((g * 512 + col * 8) ^ (((col >> 3) & 7) << 4)) + ko;
                *(__fp16*)(lds0 + off) = hai[j];
                *(__fp16*)(lds1 + off) = hbi[j];
                *(__fp16*)(lds2 + off) = haj[j];
                *(__fp16*)(lds3 + off) = hbj[j];
            }
        }
        __syncthreads();
#pragma unroll
        for (int g = 0; g < 8; ++g) {
            h2 aIl[4], aIh[4], bIl[4], bIh[4], aJl[4], aJh[4], bJl[4], bJh[4];
#pragma unroll
            for (int r = 0; r < 4; ++r) {
                const int ca = ty * 4 + r, cb = tx * 4 + r;
                const int offa = (g * 512 + ca * 8) ^ (((ca >> 3) & 7) << 4);
                const int offb = (g * 512 + cb * 8) ^ (((cb >> 3) & 7) << 4);
                h4 vA = *(const h4*)(lds0 + offa);
                h4 vB = *(const h4*)(lds1 + offa);
                h4 vC = *(const h4*)(lds2 + offb);
                h4 vD = *(const h4*)(lds3 + offb);
                aIl[r] = __builtin_shufflevector(vA, vA, 0, 1); aIh[r] = __builtin_shufflevector(vA, vA, 2, 3);
                bIl[r] = __builtin_shufflevector(vB, vB, 0, 1); bIh[r] = __builtin_shufflevector(vB, vB, 2, 3);
                aJl[r] = __builtin_shufflevector(vC, vC, 0, 1); aJh[r] = __builtin_shufflevector(vC, vC, 2, 3);
                bJl[r] = __builtin_shufflevector(vD, vD, 0, 1); bJh[r] = __builtin_shufflevector(vD, vD, 2, 3);
            }
#pragma unroll
            for (int r = 0; r < 4; ++r)
#pragma unroll
                for (int c = 0; c < 4; ++c) {
                    cIJ[r][c] = fdot2(aIl[r], bJl[c], cIJ[r][c]);
                    cIJ[r][c] = fdot2(aIh[r], bJh[c], cIJ[r][c]);
                    cJI[r][c] = fdot2(bIl[r], aJl[c], cJI[r][c]);
                    cJI[r][c] = fdot2(bIh[r], aJh[c], cJI[r][c]);
                }
        }
    }
    float ssum = 0.f;
#pragma unroll
    for (int r = 0; r < 4; ++r)
#pragma unroll
        for (int c = 0; c < 4; ++c) {
            float v = cIJ[r][c] + cJI[r][c] - 1.f;
            if (v > 0.f) ssum += v * v;
        }
    ssum *= wgt;
    ssum = wsum(ssum);
    __shared__ float red[4];
    if ((tid & 63) == 0) red[tid >> 6] = ssum;
    __syncthreads();
    if (tid == 0) dpart[b * 10 + p] = red[0] + red[1] + red[2] + red[3];
}

// ---- fused final reduction: part[4096][8] + dpart[640] -> out ----
__global__ __launch_bounds__(256) void final_kernel(const float* __restrict__ part,
                                                    const float* __restrict__ dpart,
                                                    float* __restrict__ out)
{
    const int t = threadIdx.x;
    const int b = t >> 2, qt = t & 3;     // 4 threads per batch (quad-aligned in wave)
    float v[8] = {0,0,0,0,0,0,0,0};
    for (int i = 0; i < 16; ++i) {
        const float* pp = part + ((size_t)(b * 64 + qt * 16 + i)) * 8;
        float4 x = *(const float4*)pp;
        float4 y = *(const float4*)(pp + 4);
        v[0] += x.x; v[1] += x.y; v[2] += x.z; v[3] += x.w;
        v[4] += y.x; v[5] += y.y; v[6] += y.z; v[7] += y.w;
    }
#pragma unroll
    for (int k = 0; k < 8; ++k) {
        v[k] += __shfl_xor(v[k], 1);
        v[k] += __shfl_xor(v[k], 2);
    }
    // per-batch values now replicated in the quad; qt==0 contributes
    float m = (qt == 0) ? 1.f : 0.f;
    float r0 = m * v[0], r1 = m * v[1], r2 = m * v[2], r3 = m * v[3];
    float r4 = m * v[4], r5 = m * v[5];
    float ge = m * (__expf(-v[6]) + __expf(-v[7]));
    float d = 0.f;
    for (int i = t; i < 640; i += 256) d += dpart[i];

    r0 = wsum(r0); r1 = wsum(r1); r2 = wsum(r2); r3 = wsum(r3);
    r4 = wsum(r4); r5 = wsum(r5); ge = wsum(ge); d = wsum(d);
    __shared__ float red[4][8];
    const int w = t >> 6;
    if ((t & 63) == 0) {
        red[w][0] = r0; red[w][1] = r1; red[w][2] = r2; red[w][3] = r3;
        red[w][4] = r4; red[w][5] = r5; red[w][6] = ge; red[w][7] = d;
    }
    __syncthreads();
    if (t == 0) {
        float s[8];
#pragma unroll
        for (int k = 0; k < 8; ++k)
            s[k] = red[0][k] + red[1][k] + red[2][k] + red[3][k];
        float denom = s[1] + 1e-8f;
        float type_loss = s[0] / 65536.f;
        float node = 0.5f * (s[2] / denom + s[3] / denom);
        float value = s[4] / denom;
        float self = s[5] / denom;
        float g = s[6] * (1.f / 64.f);
        float dup = s[7] / (64.f * 256.f * 256.f);
        out[0] = 1.0f * type_loss + 0.5f * node + 1.0f * value
               + 2.0f * self + 1.0f * dup + 0.5f * g;
    }
}

extern "C" void kernel_launch(void* const* d_in, const int* in_sizes, int n_in,
                              void* d_out, int out_size, void* d_ws, size_t ws_size,
                              hipStream_t stream)
{
    const float* tl   = (const float*)d_in[0];
    const float* al   = (const float*)d_in[1];
    const float* bl   = (const float*)d_in[2];
    const float* vals = (const float*)d_in[3];
    const float* seq  = (const float*)d_in[4];

    char* ws = (char*)d_ws;
    int*   cnt     = (int*)ws;
    short* slotmap = (short*)(ws + SLOT_OFF);
    float* part    = (float*)(ws + PART_OFF);
    float* dpart   = (float*)(ws + DPART_OFF);
    unsigned short* ma = (unsigned short*)(ws + MA_OFF);
    unsigned short* pb = (unsigned short*)(ws + PB_OFF);

    scan_kernel<<<64, 256, 0, stream>>>(seq, cnt, slotmap);
    stats_kernel<<<4096, 256, 0, stream>>>(tl, al, bl, vals, seq, slotmap,
                                           part, ma, pb);
    dim3 gg(10, 64);
    gemm_dup<<<gg, 256, 0, stream>>>(ma, pb, cnt, dpart);
    final_kernel<<<1, 256, 0, stream>>>(part, dpart, (float*)d_out);
}

// Round 14
// 82.530 us; speedup vs baseline: 1.0321x; 1.0321x over previous
//
#include <hip/hip_runtime.h>
#include <hip/hip_bf16.h>
#include <math.h>

#define TT 1024
#define NTYPE 16
#define NNODE 256
#define KCAP 512   // compacted masked rows per batch (expected ~192; 26 sigma headroom)

// ws layout (bytes):
//   0        : cnt[64] int
//   1024     : slotmap[64][1024] short          128 KB
//   132096   : part[4096][8] f32                128 KB
//   265216   : dpart[64][10] f32                2.5 KB
//   1048576  : ma [64][KCAP][256] f16           16 MB
//   +16M     : pb [64][KCAP][256] f16           16 MB
#define SLOT_OFF  1024
#define PART_OFF  132096
#define DPART_OFF 265216
#define MA_OFF    1048576ll
#define PB_OFF    (MA_OFF + 64ll*KCAP*256*2)

typedef __fp16 h2 __attribute__((ext_vector_type(2)));
typedef __fp16 h4 __attribute__((ext_vector_type(4)));
typedef float  f4v __attribute__((ext_vector_type(4)));

__device__ __forceinline__ float wsum(float v) {
    for (int o = 32; o > 0; o >>= 1) v += __shfl_xor(v, o);
    return v;
}
// DPP butterfly adds (VALU pipe, no LDS)
template<int CTRL>
__device__ __forceinline__ float dppadd(float v) {
    int p = __builtin_amdgcn_update_dpp(0, __float_as_int(v), CTRL, 0xF, 0xF, true);
    return v + __int_as_float(p);
}
__device__ __forceinline__ float gsum16(float v) {
    v = dppadd<0xB1>(v);    // quad_perm [1,0,3,2]
    v = dppadd<0x4E>(v);    // quad_perm [2,3,0,1]
    v = dppadd<0x141>(v);   // row_half_mirror
    v = dppadd<0x140>(v);   // row_mirror
    return v;
}
__device__ __forceinline__ unsigned pkh(float x, float y) {  // pack 2 f32 -> 2 f16
    h2 r = __builtin_amdgcn_cvt_pkrtz(x, y);
    union { h2 h; unsigned u; } c; c.h = r; return c.u;
}
__device__ __forceinline__ float fdot2(h2 a, h2 b, float c) {
#if __has_builtin(__builtin_amdgcn_fdot2)
    return __builtin_amdgcn_fdot2(a, b, c, false);
#else
    return c + (float)a[0] * (float)b[0] + (float)a[1] * (float)b[1];
#endif
}
__device__ __forceinline__ float4 ntload4(const float* p) {
    f4v v = __builtin_nontemporal_load((const f4v*)p);
    return make_float4(v.x, v.y, v.z, v.w);
}
__device__ __forceinline__ float sel4(float4 v, int e) {
    float x = (e & 1) ? v.y : v.x;
    float y = (e & 1) ? v.w : v.z;
    return (e & 2) ? y : x;
}
__device__ __forceinline__ float sel16(float4 v0, float4 v1, float4 v2, float4 v3,
                                       int j, int e) {
    float s0 = sel4(v0, e), s1 = sel4(v1, e), s2 = sel4(v2, e), s3 = sel4(v3, e);
    float c01 = (j & 1) ? s1 : s0;
    float c23 = (j & 1) ? s3 : s2;
    return (j & 2) ? c23 : c01;
}

// ---- deterministic compaction slots: per-batch prefix sum of the mask ----
__global__ __launch_bounds__(256) void scan_kernel(const float* __restrict__ seq,
                                                   int* __restrict__ cnt,
                                                   short* __restrict__ slotmap)
{
    const int b = blockIdx.x;
    const int tid = threadIdx.x;
    const int lane = tid & 63, w = tid >> 6;
    const int t0 = tid * 4;
    int m0 = 0, m1 = 0, m2 = 0, m3 = 0;
    {
        int tt;
        tt = (int)seq[((size_t)b * TT + t0 + 1) * 4];               m0 = (tt >= 3 && tt <= 5);
        tt = (int)seq[((size_t)b * TT + t0 + 2) * 4];               m1 = (tt >= 3 && tt <= 5);
        tt = (int)seq[((size_t)b * TT + t0 + 3) * 4];               m2 = (tt >= 3 && tt <= 5);
        if (t0 + 3 < TT - 1) {
            tt = (int)seq[((size_t)b * TT + t0 + 4) * 4];           m3 = (tt >= 3 && tt <= 5);
        }
    }
    int lc = m0 + m1 + m2 + m3;
    int inc = lc;
    for (int o = 1; o < 64; o <<= 1) {
        int v = __shfl_up(inc, o);
        if (lane >= o) inc += v;
    }
    __shared__ int wtot[4];
    if (lane == 63) wtot[w] = inc;
    __syncthreads();
    int woff = 0;
    for (int i = 0; i < 4; ++i) woff += (i < w) ? wtot[i] : 0;
    int run = woff + inc - lc;
    if (m0) { slotmap[(size_t)b * TT + t0 + 0] = (short)run; ++run; }
    if (m1) { slotmap[(size_t)b * TT + t0 + 1] = (short)run; ++run; }
    if (m2) { slotmap[(size_t)b * TT + t0 + 2] = (short)run; ++run; }
    if (m3) { slotmap[(size_t)b * TT + t0 + 3] = (short)run; ++run; }
    if (tid == 255) cnt[b] = woff + inc;
}

// ---- fused per-row stats: 16-lane group per row, 4 rows per wave ----
__global__ __launch_bounds__(256) void stats_kernel(
    const float* __restrict__ tl, const float* __restrict__ al,
    const float* __restrict__ bl, const float* __restrict__ vals,
    const float* __restrict__ seq, const short* __restrict__ slotmap,
    float* __restrict__ part,
    unsigned short* __restrict__ ma, unsigned short* __restrict__ pb)
{
    const int tid = threadIdx.x;
    const int w = tid >> 6, lane = tid & 63;
    const int s = lane & 15;                       // sublane within 16-lane group
    const int rowbase = blockIdx.x * 16 + w * 4;
    const int row = rowbase + (lane >> 4);
    const int b = row >> 10, t = row & 1023;

    // shifted target (group-uniform)
    float4 tgt = make_float4(0.f, 0.f, 0.f, 0.f);
    if (t < TT - 1) tgt = *(const float4*)(seq + (size_t)(row + 1) * 4);
    const int   t_type = (int)tgt.x;
    const int   t_a    = (int)tgt.y;
    const int   t_b    = (int)tgt.z;
    const float t_val  = tgt.w;
    const float mask   = (t_type >= 3 && t_type <= 5) ? 1.f : 0.f;

    // ---- type softmax: exactly 1 logit per sublane ----
    float tlv = tl[(size_t)rowbase * 16 + lane];
    float te  = __expf(tlv);
    float tsum = gsum16(te);
    float tcs  = gsum16((s >= 3 && s <= 5) ? te : 0.f);
    float p_comp = tcs / tsum;
    float ce_type = __logf(tsum) - __shfl(tlv, (lane & 48) + t_type);

    // ---- node a/b: 16 logits per sublane (4 x float4, stride-64 chunks) ----
    const float* arow = al + (size_t)row * 256;
    float4 a0 = ntload4(arow + s * 4);
    float4 a1 = ntload4(arow + s * 4 + 64);
    float4 a2 = ntload4(arow + s * 4 + 128);
    float4 a3 = ntload4(arow + s * 4 + 192);
    const float* brow = bl + (size_t)row * 256;
    float4 b0 = ntload4(brow + s * 4);
    float4 b1 = ntload4(brow + s * 4 + 64);
    float4 b2 = ntload4(brow + s * 4 + 128);
    float4 b3 = ntload4(brow + s * 4 + 192);

    // CE gathers on raw logits
    const int ja = t_a >> 6, sa = (t_a >> 2) & 15, ea = t_a & 3;
    const int jb = t_b >> 6, sb = (t_b >> 2) & 15, eb = t_b & 3;
    float ga = __shfl(sel16(a0, a1, a2, a3, ja, ea), (lane & 48) + sa);
    float gb = __shfl(sel16(b0, b1, b2, b3, jb, eb), (lane & 48) + sb);

    float ea0x = __expf(a0.x), ea0y = __expf(a0.y), ea0z = __expf(a0.z), ea0w = __expf(a0.w);
    float ea1x = __expf(a1.x), ea1y = __expf(a1.y), ea1z = __expf(a1.z), ea1w = __expf(a1.w);
    float ea2x = __expf(a2.x), ea2y = __expf(a2.y), ea2z = __expf(a2.z), ea2w = __expf(a2.w);
    float ea3x = __expf(a3.x), ea3y = __expf(a3.y), ea3z = __expf(a3.z), ea3w = __expf(a3.w);
    float eb0x = __expf(b0.x), eb0y = __expf(b0.y), eb0z = __expf(b0.z), eb0w = __expf(b0.w);
    float eb1x = __expf(b1.x), eb1y = __expf(b1.y), eb1z = __expf(b1.z), eb1w = __expf(b1.w);
    float eb2x = __expf(b2.x), eb2y = __expf(b2.y), eb2z = __expf(b2.z), eb2w = __expf(b2.w);
    float eb3x = __expf(b3.x), eb3y = __expf(b3.y), eb3z = __expf(b3.z), eb3w = __expf(b3.w);

    float lsa = ((ea0x + ea0y) + (ea0z + ea0w)) + ((ea1x + ea1y) + (ea1z + ea1w))
              + ((ea2x + ea2y) + (ea2z + ea2w)) + ((ea3x + ea3y) + (ea3z + ea3w));
    float lsb = ((eb0x + eb0y) + (eb0z + eb0w)) + ((eb1x + eb1y) + (eb1z + eb1w))
              + ((eb2x + eb2y) + (eb2z + eb2w)) + ((eb3x + eb3y) + (eb3z + eb3w));
    float asum = gsum16(lsa);
    float bsum = gsum16(lsb);
    float ainv = 1.f / asum, binv = 1.f / bsum;

    float ce_a = __logf(asum) - ga;
    float ce_b = __logf(bsum) - gb;

    // selfloop dot
    float dl = ((ea0x * eb0x + ea0y * eb0y) + (ea0z * eb0z + ea0w * eb0w))
             + ((ea1x * eb1x + ea1y * eb1y) + (ea1z * eb1z + ea1w * eb1w))
             + ((ea2x * eb2x + ea2y * eb2y) + (ea2z * eb2z + ea2w * eb2w))
             + ((ea3x * eb3x + ea3y * eb3y) + (ea3z * eb3z + ea3w * eb3w));
    float dot = gsum16(dl) * ainv * binv;

    // gnd: node cols 0,1 live on sublane 0 elements x,y
    float s0c = ((ea0x * ainv) + (eb0x * binv)) * p_comp;
    float s1c = ((ea0y * ainv) + (eb0y * binv)) * p_comp;

    float pv = vals[row];
    float vloss = mask * (pv - t_val) * (pv - t_val);

    // ---- compacted f16 prob rows ----
    if (mask > 0.f) {
        int slot = slotmap[row];
        if (slot < KCAP) {
            size_t base = ((size_t)b * KCAP + slot) * 256 + s * 4;
            *(uint2*)(ma + base)       = make_uint2(pkh(ea0x * ainv, ea0y * ainv), pkh(ea0z * ainv, ea0w * ainv));
            *(uint2*)(ma + base + 64)  = make_uint2(pkh(ea1x * ainv, ea1y * ainv), pkh(ea1z * ainv, ea1w * ainv));
            *(uint2*)(ma + base + 128) = make_uint2(pkh(ea2x * ainv, ea2y * ainv), pkh(ea2z * ainv, ea2w * ainv));
            *(uint2*)(ma + base + 192) = make_uint2(pkh(ea3x * ainv, ea3y * ainv), pkh(ea3z * ainv, ea3w * ainv));
            *(uint2*)(pb + base)       = make_uint2(pkh(eb0x * binv, eb0y * binv), pkh(eb0z * binv, eb0w * binv));
            *(uint2*)(pb + base + 64)  = make_uint2(pkh(eb1x * binv, eb1y * binv), pkh(eb1z * binv, eb1w * binv));
            *(uint2*)(pb + base + 128) = make_uint2(pkh(eb2x * binv, eb2y * binv), pkh(eb2z * binv, eb2w * binv));
            *(uint2*)(pb + base + 192) = make_uint2(pkh(eb3x * binv, eb3y * binv), pkh(eb3z * binv, eb3w * binv));
        }
    }

    // ---- reduce 8 scalars: group leaders, then xor16+xor32 across groups ----
    float r0 = (s == 0) ? ce_type       : 0.f;
    float r1 = (s == 0) ? mask          : 0.f;
    float r2 = (s == 0) ? mask * ce_a   : 0.f;
    float r3 = (s == 0) ? mask * ce_b   : 0.f;
    float r4 = (s == 0) ? vloss         : 0.f;
    float r5 = (s == 0) ? mask * dot    : 0.f;
    float r6 = (s == 0) ? s0c           : 0.f;
    float r7 = (s == 0) ? s1c           : 0.f;
#define XR(v) v += __shfl_xor(v, 16); v += __shfl_xor(v, 32);
    XR(r0) XR(r1) XR(r2) XR(r3) XR(r4) XR(r5) XR(r6) XR(r7)
#undef XR
    __shared__ float red[4][8];
    if (lane == 0) {
        red[w][0] = r0; red[w][1] = r1; red[w][2] = r2; red[w][3] = r3;
        red[w][4] = r4; red[w][5] = r5; red[w][6] = r6; red[w][7] = r7;
    }
    __syncthreads();
    if (tid < 8) {
        part[(size_t)blockIdx.x * 8 + tid] =
            red[0][tid] + red[1][tid] + red[2][tid] + red[3][tid];
    }
}

// ---- fused ec GEMM + dup penalty: 64x64 tile pairs, 512 threads ----
// K-chunk 64; waves 0-3 compute k-half 0 (g=0..7), waves 4-7 k-half 1 (g=8..15).
// Partial accumulators combined via LDS BEFORE the relu^2 nonlinearity.
// LDS granule layout (per 8KB array): off(g,c) = g*512 + (c&3)*128 + (c>>2)*8
//   -> compute reads land on banks 2*tx (perfect 32-bank tile, zero conflict);
//      staging b16 writes are <=2 dwords/bank (free-ish).
__constant__ int cTI[10] = {0, 1, 2, 3, 0, 0, 0, 1, 1, 2};
__constant__ int cTJ[10] = {0, 1, 2, 3, 1, 2, 3, 2, 3, 3};

__global__ __launch_bounds__(512) void gemm_dup(
    const unsigned short* __restrict__ ma, const unsigned short* __restrict__ pb,
    const int* __restrict__ cnt, float* __restrict__ dpart)
{
    __shared__ __align__(16) char lds[32768];
    char* lds0 = lds;
    char* lds1 = lds + 8192;
    char* lds2 = lds + 16384;
    char* lds3 = lds + 24576;
    const int b = blockIdx.y;
    int K = cnt[b]; if (K > KCAP) K = KCAP;
    const int p = blockIdx.x;
    const int I0 = cTI[p] * 64, J0 = cTJ[p] * 64;
    const float wgt = (I0 == J0) ? 1.f : 2.f;
    const int tid = threadIdx.x;
    const int lr = tid >> 3, lc = (tid & 7) * 8;   // staging: 64 k-rows x 64 cols
    const int h  = tid >> 8;                       // k-half for compute
    const int t8 = tid & 255;
    const int tx = t8 & 15, ty = t8 >> 4;
    const size_t bb = (size_t)b * KCAP * 256;
    float cIJ[4][4] = {};   // partial over this half's k
    float cJI[4][4] = {};

    for (int k0 = 0; k0 < K; k0 += 64) {
        const int kr = k0 + lr;
        uint4 vai = make_uint4(0,0,0,0), vbi = vai, vaj = vai, vbj = vai;
        if (kr < K) {
            size_t rb = bb + (size_t)kr * 256;
            vai = *(const uint4*)(ma + rb + I0 + lc);
            vbi = *(const uint4*)(pb + rb + I0 + lc);
            vaj = *(const uint4*)(ma + rb + J0 + lc);
            vbj = *(const uint4*)(pb + rb + J0 + lc);
        }
        __syncthreads();
        {
            const int g = lr >> 2;
            const int ko = (lr & 3) * 2;
            const __fp16* hai = (const __fp16*)&vai;
            const __fp16* hbi = (const __fp16*)&vbi;
            const __fp16* haj = (const __fp16*)&vaj;
            const __fp16* hbj = (const __fp16*)&vbj;
#pragma unroll
            for (int j = 0; j < 8; ++j) {
                const int cg = (tid & 7) * 2 + (j >> 2);       // (col>>2)
                const int off = g * 512 + (j & 3) * 128 + cg * 8 + ko;
                *(__fp16*)(lds0 + off) = hai[j];
                *(__fp16*)(lds1 + off) = hbi[j];
                *(__fp16*)(lds2 + off) = haj[j];
                *(__fp16*)(lds3 + off) = hbj[j];
            }
        }
        __syncthreads();
#pragma unroll
        for (int gg = 0; gg < 8; ++gg) {
            const int g = h * 8 + gg;
            h2 aIl[4], aIh[4], bIl[4], bIh[4], aJl[4], aJh[4], bJl[4], bJh[4];
#pragma unroll
            for (int r = 0; r < 4; ++r) {
                const int offa = g * 512 + r * 128 + ty * 8;   // ca = ty*4+r
                const int offb = g * 512 + r * 128 + tx * 8;   // cb = tx*4+r
                h4 vA = *(const h4*)(lds0 + offa);
                h4 vB = *(const h4*)(lds1 + offa);
                h4 vC = *(const h4*)(lds2 + offb);
                h4 vD = *(const h4*)(lds3 + offb);
                aIl[r] = __builtin_shufflevector(vA, vA, 0, 1); aIh[r] = __builtin_shufflevector(vA, vA, 2, 3);
                bIl[r] = __builtin_shufflevector(vB, vB, 0, 1); bIh[r] = __builtin_shufflevector(vB, vB, 2, 3);
                aJl[r] = __builtin_shufflevector(vC, vC, 0, 1); aJh[r] = __builtin_shufflevector(vC, vC, 2, 3);
                bJl[r] = __builtin_shufflevector(vD, vD, 0, 1); bJh[r] = __builtin_shufflevector(vD, vD, 2, 3);
            }
#pragma unroll
            for (int r = 0; r < 4; ++r)
#pragma unroll
                for (int c = 0; c < 4; ++c) {
                    cIJ[r][c] = fdot2(aIl[r], bJl[c], cIJ[r][c]);
                    cIJ[r][c] = fdot2(aIh[r], bJh[c], cIJ[r][c]);
                    cJI[r][c] = fdot2(bIl[r], aJl[c], cJI[r][c]);
                    cJI[r][c] = fdot2(bIh[r], aJh[c], cJI[r][c]);
                }
        }
    }

    // ---- combine the two k-halves (before the nonlinearity) ----
    __syncthreads();
    float* sf = (float*)lds;          // 8192 floats; layout [32 idx][256 t8] -> conflict-free
    if (h == 1) {
#pragma unroll
        for (int r = 0; r < 4; ++r)
#pragma unroll
            for (int c = 0; c < 4; ++c) {
                sf[(r * 4 + c) * 256 + t8]        = cIJ[r][c];
                sf[(16 + r * 4 + c) * 256 + t8]   = cJI[r][c];
            }
    }
    __syncthreads();
    float ssum = 0.f;
    if (h == 0) {
#pragma unroll
        for (int r = 0; r < 4; ++r)
#pragma unroll
            for (int c = 0; c < 4; ++c) {
                float vij = cIJ[r][c] + sf[(r * 4 + c) * 256 + t8];
                float vji = cJI[r][c] + sf[(16 + r * 4 + c) * 256 + t8];
                float v = vij + vji - 1.f;
                if (v > 0.f) ssum += v * v;
            }
        ssum *= wgt;
    }
    ssum = wsum(ssum);
    __shared__ float red[8];
    if ((tid & 63) == 0) red[tid >> 6] = ssum;
    __syncthreads();
    if (tid == 0) {
        float d = 0.f;
#pragma unroll
        for (int i = 0; i < 8; ++i) d += red[i];
        dpart[b * 10 + p] = d;
    }
}

// ---- fused final reduction: part[4096][8] + dpart[640] -> out ----
__global__ __launch_bounds__(256) void final_kernel(const float* __restrict__ part,
                                                    const float* __restrict__ dpart,
                                                    float* __restrict__ out)
{
    const int t = threadIdx.x;
    const int b = t >> 2, qt = t & 3;     // 4 threads per batch (quad-aligned in wave)
    float v[8] = {0,0,0,0,0,0,0,0};
    for (int i = 0; i < 16; ++i) {
        const float* pp = part + ((size_t)(b * 64 + qt * 16 + i)) * 8;
        float4 x = *(const float4*)pp;
        float4 y = *(const float4*)(pp + 4);
        v[0] += x.x; v[1] += x.y; v[2] += x.z; v[3] += x.w;
        v[4] += y.x; v[5] += y.y; v[6] += y.z; v[7] += y.w;
    }
#pragma unroll
    for (int k = 0; k < 8; ++k) {
        v[k] += __shfl_xor(v[k], 1);
        v[k] += __shfl_xor(v[k], 2);
    }
    // per-batch values now replicated in the quad; qt==0 contributes
    float m = (qt == 0) ? 1.f : 0.f;
    float r0 = m * v[0], r1 = m * v[1], r2 = m * v[2], r3 = m * v[3];
    float r4 = m * v[4], r5 = m * v[5];
    float ge = m * (__expf(-v[6]) + __expf(-v[7]));
    float d = 0.f;
    for (int i = t; i < 640; i += 256) d += dpart[i];

    r0 = wsum(r0); r1 = wsum(r1); r2 = wsum(r2); r3 = wsum(r3);
    r4 = wsum(r4); r5 = wsum(r5); ge = wsum(ge); d = wsum(d);
    __shared__ float red[4][8];
    const int w = t >> 6;
    if ((t & 63) == 0) {
        red[w][0] = r0; red[w][1] = r1; red[w][2] = r2; red[w][3] = r3;
        red[w][4] = r4; red[w][5] = r5; red[w][6] = ge; red[w][7] = d;
    }
    __syncthreads();
    if (t == 0) {
        float s[8];
#pragma unroll
        for (int k = 0; k < 8; ++k)
            s[k] = red[0][k] + red[1][k] + red[2][k] + red[3][k];
        float denom = s[1] + 1e-8f;
        float type_loss = s[0] / 65536.f;
        float node = 0.5f * (s[2] / denom + s[3] / denom);
        float value = s[4] / denom;
        float self = s[5] / denom;
        float g = s[6] * (1.f / 64.f);
        float dup = s[7] / (64.f * 256.f * 256.f);
        out[0] = 1.0f * type_loss + 0.5f * node + 1.0f * value
               + 2.0f * self + 1.0f * dup + 0.5f * g;
    }
}

extern "C" void kernel_launch(void* const* d_in, const int* in_sizes, int n_in,
                              void* d_out, int out_size, void* d_ws, size_t ws_size,
                              hipStream_t stream)
{
    const float* tl   = (const float*)d_in[0];
    const float* al   = (const float*)d_in[1];
    const float* bl   = (const float*)d_in[2];
    const float* vals = (const float*)d_in[3];
    const float* seq  = (const float*)d_in[4];

    char* ws = (char*)d_ws;
    int*   cnt     = (int*)ws;
    short* slotmap = (short*)(ws + SLOT_OFF);
    float* part    = (float*)(ws + PART_OFF);
    float* dpart   = (float*)(ws + DPART_OFF);
    unsigned short* ma = (unsigned short*)(ws + MA_OFF);
    unsigned short* pb = (unsigned short*)(ws + PB_OFF);

    scan_kernel<<<64, 256, 0, stream>>>(seq, cnt, slotmap);
    stats_kernel<<<4096, 256, 0, stream>>>(tl, al, bl, vals, seq, slotmap,
                                           part, ma, pb);
    dim3 gg(10, 64);
    gemm_dup<<<gg, 512, 0, stream>>>(ma, pb, cnt, dpart);
    final_kernel<<<1, 256, 0, stream>>>(part, dpart, (float*)d_out);
}

// Round 15
// 60.251 us; speedup vs baseline: 1.4137x; 1.3698x over previous
//
#include <hip/hip_runtime.h>
#include <hip/hip_bf16.h>
#include <math.h>

#define TT 1024
#define NTYPE 16
#define NNODE 256
#define KCAP 512   // compacted masked rows per batch (expected ~192; 26 sigma headroom)

// ws layout (bytes):
//   0        : cnt[64] int
//   512      : skip[64] int  (dup-pen Cauchy-Schwarz bound verdict per batch)
//   1024     : slotmap[64][1024] short          128 KB
//   132096   : part[4096][8] f32                128 KB
//   265216   : dpart[64][10] f32                2.5 KB
//   1048576  : ma [64][KCAP][256] f16           16 MB
//   +16M     : pb [64][KCAP][256] f16           16 MB
#define SKIP_OFF  512
#define SLOT_OFF  1024
#define PART_OFF  132096
#define DPART_OFF 265216
#define MA_OFF    1048576ll
#define PB_OFF    (MA_OFF + 64ll*KCAP*256*2)

typedef __fp16 h2 __attribute__((ext_vector_type(2)));
typedef __fp16 h4 __attribute__((ext_vector_type(4)));
typedef float  f4v __attribute__((ext_vector_type(4)));

__device__ __forceinline__ float wsum(float v) {
    for (int o = 32; o > 0; o >>= 1) v += __shfl_xor(v, o);
    return v;
}
__device__ __forceinline__ float wmaxr(float v) {
    for (int o = 32; o > 0; o >>= 1) v = fmaxf(v, __shfl_xor(v, o));
    return v;
}
// DPP butterfly adds (VALU pipe, no LDS)
template<int CTRL>
__device__ __forceinline__ float dppadd(float v) {
    int p = __builtin_amdgcn_update_dpp(0, __float_as_int(v), CTRL, 0xF, 0xF, true);
    return v + __int_as_float(p);
}
__device__ __forceinline__ float gsum16(float v) {
    v = dppadd<0xB1>(v);    // quad_perm [1,0,3,2]
    v = dppadd<0x4E>(v);    // quad_perm [2,3,0,1]
    v = dppadd<0x141>(v);   // row_half_mirror
    v = dppadd<0x140>(v);   // row_mirror
    return v;
}
__device__ __forceinline__ unsigned pkh(float x, float y) {  // pack 2 f32 -> 2 f16
    h2 r = __builtin_amdgcn_cvt_pkrtz(x, y);
    union { h2 h; unsigned u; } c; c.h = r; return c.u;
}
__device__ __forceinline__ float fdot2(h2 a, h2 b, float c) {
#if __has_builtin(__builtin_amdgcn_fdot2)
    return __builtin_amdgcn_fdot2(a, b, c, false);
#else
    return c + (float)a[0] * (float)b[0] + (float)a[1] * (float)b[1];
#endif
}
__device__ __forceinline__ float4 ntload4(const float* p) {
    f4v v = __builtin_nontemporal_load((const f4v*)p);
    return make_float4(v.x, v.y, v.z, v.w);
}
__device__ __forceinline__ float sel4(float4 v, int e) {
    float x = (e & 1) ? v.y : v.x;
    float y = (e & 1) ? v.w : v.z;
    return (e & 2) ? y : x;
}
__device__ __forceinline__ float sel16(float4 v0, float4 v1, float4 v2, float4 v3,
                                       int j, int e) {
    float s0 = sel4(v0, e), s1 = sel4(v1, e), s2 = sel4(v2, e), s3 = sel4(v3, e);
    float c01 = (j & 1) ? s1 : s0;
    float c23 = (j & 1) ? s3 : s2;
    return (j & 2) ? c23 : c01;
}

// ---- deterministic compaction slots: per-batch prefix sum of the mask ----
__global__ __launch_bounds__(256) void scan_kernel(const float* __restrict__ seq,
                                                   int* __restrict__ cnt,
                                                   short* __restrict__ slotmap)
{
    const int b = blockIdx.x;
    const int tid = threadIdx.x;
    const int lane = tid & 63, w = tid >> 6;
    const int t0 = tid * 4;
    int m0 = 0, m1 = 0, m2 = 0, m3 = 0;
    {
        int tt;
        tt = (int)seq[((size_t)b * TT + t0 + 1) * 4];               m0 = (tt >= 3 && tt <= 5);
        tt = (int)seq[((size_t)b * TT + t0 + 2) * 4];               m1 = (tt >= 3 && tt <= 5);
        tt = (int)seq[((size_t)b * TT + t0 + 3) * 4];               m2 = (tt >= 3 && tt <= 5);
        if (t0 + 3 < TT - 1) {
            tt = (int)seq[((size_t)b * TT + t0 + 4) * 4];           m3 = (tt >= 3 && tt <= 5);
        }
    }
    int lc = m0 + m1 + m2 + m3;
    int inc = lc;
    for (int o = 1; o < 64; o <<= 1) {
        int v = __shfl_up(inc, o);
        if (lane >= o) inc += v;
    }
    __shared__ int wtot[4];
    if (lane == 63) wtot[w] = inc;
    __syncthreads();
    int woff = 0;
    for (int i = 0; i < 4; ++i) woff += (i < w) ? wtot[i] : 0;
    int run = woff + inc - lc;
    if (m0) { slotmap[(size_t)b * TT + t0 + 0] = (short)run; ++run; }
    if (m1) { slotmap[(size_t)b * TT + t0 + 1] = (short)run; ++run; }
    if (m2) { slotmap[(size_t)b * TT + t0 + 2] = (short)run; ++run; }
    if (m3) { slotmap[(size_t)b * TT + t0 + 3] = (short)run; ++run; }
    if (tid == 255) cnt[b] = woff + inc;
}

// ---- fused per-row stats: 16-lane group per row, 4 rows per wave ----
__global__ __launch_bounds__(256) void stats_kernel(
    const float* __restrict__ tl, const float* __restrict__ al,
    const float* __restrict__ bl, const float* __restrict__ vals,
    const float* __restrict__ seq, const short* __restrict__ slotmap,
    float* __restrict__ part,
    unsigned short* __restrict__ ma, unsigned short* __restrict__ pb)
{
    const int tid = threadIdx.x;
    const int w = tid >> 6, lane = tid & 63;
    const int s = lane & 15;                       // sublane within 16-lane group
    const int rowbase = blockIdx.x * 16 + w * 4;
    const int row = rowbase + (lane >> 4);
    const int b = row >> 10, t = row & 1023;

    // shifted target (group-uniform)
    float4 tgt = make_float4(0.f, 0.f, 0.f, 0.f);
    if (t < TT - 1) tgt = *(const float4*)(seq + (size_t)(row + 1) * 4);
    const int   t_type = (int)tgt.x;
    const int   t_a    = (int)tgt.y;
    const int   t_b    = (int)tgt.z;
    const float t_val  = tgt.w;
    const float mask   = (t_type >= 3 && t_type <= 5) ? 1.f : 0.f;

    // ---- type softmax: exactly 1 logit per sublane ----
    float tlv = tl[(size_t)rowbase * 16 + lane];
    float te  = __expf(tlv);
    float tsum = gsum16(te);
    float tcs  = gsum16((s >= 3 && s <= 5) ? te : 0.f);
    float p_comp = tcs / tsum;
    float ce_type = __logf(tsum) - __shfl(tlv, (lane & 48) + t_type);

    // ---- node a/b: 16 logits per sublane (4 x float4, stride-64 chunks) ----
    const float* arow = al + (size_t)row * 256;
    float4 a0 = ntload4(arow + s * 4);
    float4 a1 = ntload4(arow + s * 4 + 64);
    float4 a2 = ntload4(arow + s * 4 + 128);
    float4 a3 = ntload4(arow + s * 4 + 192);
    const float* brow = bl + (size_t)row * 256;
    float4 b0 = ntload4(brow + s * 4);
    float4 b1 = ntload4(brow + s * 4 + 64);
    float4 b2 = ntload4(brow + s * 4 + 128);
    float4 b3 = ntload4(brow + s * 4 + 192);

    // CE gathers on raw logits
    const int ja = t_a >> 6, sa = (t_a >> 2) & 15, ea = t_a & 3;
    const int jb = t_b >> 6, sb = (t_b >> 2) & 15, eb = t_b & 3;
    float ga = __shfl(sel16(a0, a1, a2, a3, ja, ea), (lane & 48) + sa);
    float gb = __shfl(sel16(b0, b1, b2, b3, jb, eb), (lane & 48) + sb);

    float ea0x = __expf(a0.x), ea0y = __expf(a0.y), ea0z = __expf(a0.z), ea0w = __expf(a0.w);
    float ea1x = __expf(a1.x), ea1y = __expf(a1.y), ea1z = __expf(a1.z), ea1w = __expf(a1.w);
    float ea2x = __expf(a2.x), ea2y = __expf(a2.y), ea2z = __expf(a2.z), ea2w = __expf(a2.w);
    float ea3x = __expf(a3.x), ea3y = __expf(a3.y), ea3z = __expf(a3.z), ea3w = __expf(a3.w);
    float eb0x = __expf(b0.x), eb0y = __expf(b0.y), eb0z = __expf(b0.z), eb0w = __expf(b0.w);
    float eb1x = __expf(b1.x), eb1y = __expf(b1.y), eb1z = __expf(b1.z), eb1w = __expf(b1.w);
    float eb2x = __expf(b2.x), eb2y = __expf(b2.y), eb2z = __expf(b2.z), eb2w = __expf(b2.w);
    float eb3x = __expf(b3.x), eb3y = __expf(b3.y), eb3z = __expf(b3.z), eb3w = __expf(b3.w);

    float lsa = ((ea0x + ea0y) + (ea0z + ea0w)) + ((ea1x + ea1y) + (ea1z + ea1w))
              + ((ea2x + ea2y) + (ea2z + ea2w)) + ((ea3x + ea3y) + (ea3z + ea3w));
    float lsb = ((eb0x + eb0y) + (eb0z + eb0w)) + ((eb1x + eb1y) + (eb1z + eb1w))
              + ((eb2x + eb2y) + (eb2z + eb2w)) + ((eb3x + eb3y) + (eb3z + eb3w));
    float asum = gsum16(lsa);
    float bsum = gsum16(lsb);
    float ainv = 1.f / asum, binv = 1.f / bsum;

    float ce_a = __logf(asum) - ga;
    float ce_b = __logf(bsum) - gb;

    // selfloop dot
    float dl = ((ea0x * eb0x + ea0y * eb0y) + (ea0z * eb0z + ea0w * eb0w))
             + ((ea1x * eb1x + ea1y * eb1y) + (ea1z * eb1z + ea1w * eb1w))
             + ((ea2x * eb2x + ea2y * eb2y) + (ea2z * eb2z + ea2w * eb2w))
             + ((ea3x * eb3x + ea3y * eb3y) + (ea3z * eb3z + ea3w * eb3w));
    float dot = gsum16(dl) * ainv * binv;

    // gnd: node cols 0,1 live on sublane 0 elements x,y
    float s0c = ((ea0x * ainv) + (eb0x * binv)) * p_comp;
    float s1c = ((ea0y * ainv) + (eb0y * binv)) * p_comp;

    float pv = vals[row];
    float vloss = mask * (pv - t_val) * (pv - t_val);

    // ---- compacted f16 prob rows ----
    if (mask > 0.f) {
        int slot = slotmap[row];
        if (slot < KCAP) {
            size_t base = ((size_t)b * KCAP + slot) * 256 + s * 4;
            *(uint2*)(ma + base)       = make_uint2(pkh(ea0x * ainv, ea0y * ainv), pkh(ea0z * ainv, ea0w * ainv));
            *(uint2*)(ma + base + 64)  = make_uint2(pkh(ea1x * ainv, ea1y * ainv), pkh(ea1z * ainv, ea1w * ainv));
            *(uint2*)(ma + base + 128) = make_uint2(pkh(ea2x * ainv, ea2y * ainv), pkh(ea2z * ainv, ea2w * ainv));
            *(uint2*)(ma + base + 192) = make_uint2(pkh(ea3x * ainv, ea3y * ainv), pkh(ea3z * ainv, ea3w * ainv));
            *(uint2*)(pb + base)       = make_uint2(pkh(eb0x * binv, eb0y * binv), pkh(eb0z * binv, eb0w * binv));
            *(uint2*)(pb + base + 64)  = make_uint2(pkh(eb1x * binv, eb1y * binv), pkh(eb1z * binv, eb1w * binv));
            *(uint2*)(pb + base + 128) = make_uint2(pkh(eb2x * binv, eb2y * binv), pkh(eb2z * binv, eb2w * binv));
            *(uint2*)(pb + base + 192) = make_uint2(pkh(eb3x * binv, eb3y * binv), pkh(eb3z * binv, eb3w * binv));
        }
    }

    // ---- reduce 8 scalars: group leaders, then xor16+xor32 across groups ----
    float r0 = (s == 0) ? ce_type       : 0.f;
    float r1 = (s == 0) ? mask          : 0.f;
    float r2 = (s == 0) ? mask * ce_a   : 0.f;
    float r3 = (s == 0) ? mask * ce_b   : 0.f;
    float r4 = (s == 0) ? vloss         : 0.f;
    float r5 = (s == 0) ? mask * dot    : 0.f;
    float r6 = (s == 0) ? s0c           : 0.f;
    float r7 = (s == 0) ? s1c           : 0.f;
#define XR(v) v += __shfl_xor(v, 16); v += __shfl_xor(v, 32);
    XR(r0) XR(r1) XR(r2) XR(r3) XR(r4) XR(r5) XR(r6) XR(r7)
#undef XR
    __shared__ float red[4][8];
    if (lane == 0) {
        red[w][0] = r0; red[w][1] = r1; red[w][2] = r2; red[w][3] = r3;
        red[w][4] = r4; red[w][5] = r5; red[w][6] = r6; red[w][7] = r7;
    }
    __syncthreads();
    if (tid < 8) {
        part[(size_t)blockIdx.x * 8 + tid] =
            red[0][tid] + red[1][tid] + red[2][tid] + red[3][tid];
    }
}

// ---- per-batch column-norm bound (Cauchy-Schwarz):
// ec[i][j] <= ||ma_col_i||*||pb_col_j||, so if 4*maxSA*maxSB < 0.25
// (safety factor 2 over the needed <=1), every ec_sym entry < 1 and
// relu(ec_sym-1)^2 == 0 EXACTLY. skip[b]=1 lets gemm_dup early-exit;
// otherwise the full GEMM runs (correct for any input).
__global__ __launch_bounds__(1024) void norm_kernel(
    const unsigned short* __restrict__ ma, const unsigned short* __restrict__ pb,
    const int* __restrict__ cnt, int* __restrict__ skip)
{
    const int b = blockIdx.x;
    int K = cnt[b]; if (K > KCAP) K = KCAP;
    const int i  = threadIdx.x & 255;   // column
    const int st = threadIdx.x >> 8;    // k-strip 0..3
    const size_t bb = (size_t)b * KCAP * 256;
    const __fp16* mah = (const __fp16*)(ma + bb);
    const __fp16* pbh = (const __fp16*)(pb + bb);
    float sa = 0.f, sb = 0.f;
    for (int k = st; k < K; k += 4) {
        float va = (float)mah[(size_t)k * 256 + i];
        float vb = (float)pbh[(size_t)k * 256 + i];
        sa += va * va;
        sb += vb * vb;
    }
    __shared__ float sA[1024], sB[1024];
    sA[threadIdx.x] = sa; sB[threadIdx.x] = sb;
    __syncthreads();
    if (st == 0) {
        sa = sA[i] + sA[256 + i] + sA[512 + i] + sA[768 + i];   // ||col_i||^2
        sb = sB[i] + sB[256 + i] + sB[512 + i] + sB[768 + i];
        sa = wmaxr(sa);
        sb = wmaxr(sb);
        __shared__ float mxa[4], mxb[4];
        if ((threadIdx.x & 63) == 0) { mxa[i >> 6] = sa; mxb[i >> 6] = sb; }
        __syncthreads();
        if (threadIdx.x == 0) {
            float MA = fmaxf(fmaxf(mxa[0], mxa[1]), fmaxf(mxa[2], mxa[3]));
            float MB = fmaxf(fmaxf(mxb[0], mxb[1]), fmaxf(mxb[2], mxb[3]));
            skip[b] = (4.f * MA * MB < 0.25f) ? 1 : 0;
        }
    }
}

// ---- fused ec GEMM + dup penalty (fallback path; early-exits when bound holds) ----
__constant__ int cTI[10] = {0, 1, 2, 3, 0, 0, 0, 1, 1, 2};
__constant__ int cTJ[10] = {0, 1, 2, 3, 1, 2, 3, 2, 3, 3};

__global__ __launch_bounds__(512) void gemm_dup(
    const unsigned short* __restrict__ ma, const unsigned short* __restrict__ pb,
    const int* __restrict__ cnt, const int* __restrict__ skip,
    float* __restrict__ dpart)
{
    const int b = blockIdx.y;
    const int p = blockIdx.x;
    if (skip[b]) {                      // dup contribution provably zero
        if (threadIdx.x == 0) dpart[b * 10 + p] = 0.f;
        return;
    }
    __shared__ __align__(16) char lds[32768];
    char* lds0 = lds;
    char* lds1 = lds + 8192;
    char* lds2 = lds + 16384;
    char* lds3 = lds + 24576;
    int K = cnt[b]; if (K > KCAP) K = KCAP;
    const int I0 = cTI[p] * 64, J0 = cTJ[p] * 64;
    const float wgt = (I0 == J0) ? 1.f : 2.f;
    const int tid = threadIdx.x;
    const int lr = tid >> 3, lc = (tid & 7) * 8;   // staging: 64 k-rows x 64 cols
    const int h  = tid >> 8;                       // k-half for compute
    const int t8 = tid & 255;
    const int tx = t8 & 15, ty = t8 >> 4;
    const size_t bb = (size_t)b * KCAP * 256;
    float cIJ[4][4] = {};
    float cJI[4][4] = {};

    for (int k0 = 0; k0 < K; k0 += 64) {
        const int kr = k0 + lr;
        uint4 vai = make_uint4(0,0,0,0), vbi = vai, vaj = vai, vbj = vai;
        if (kr < K) {
            size_t rb = bb + (size_t)kr * 256;
            vai = *(const uint4*)(ma + rb + I0 + lc);
            vbi = *(const uint4*)(pb + rb + I0 + lc);
            vaj = *(const uint4*)(ma + rb + J0 + lc);
            vbj = *(const uint4*)(pb + rb + J0 + lc);
        }
        __syncthreads();
        {
            const int g = lr >> 2;
            const int ko = (lr & 3) * 2;
            const __fp16* hai = (const __fp16*)&vai;
            const __fp16* hbi = (const __fp16*)&vbi;
            const __fp16* haj = (const __fp16*)&vaj;
            const __fp16* hbj = (const __fp16*)&vbj;
#pragma unroll
            for (int j = 0; j < 8; ++j) {
                const int cg = (tid & 7) * 2 + (j >> 2);
                const int off = g * 512 + (j & 3) * 128 + cg * 8 + ko;
                *(__fp16*)(lds0 + off) = hai[j];
                *(__fp16*)(lds1 + off) = hbi[j];
                *(__fp16*)(lds2 + off) = haj[j];
                *(__fp16*)(lds3 + off) = hbj[j];
            }
        }
        __syncthreads();
#pragma unroll
        for (int gg = 0; gg < 8; ++gg) {
            const int g = h * 8 + gg;
            h2 aIl[4], aIh[4], bIl[4], bIh[4], aJl[4], aJh[4], bJl[4], bJh[4];
#pragma unroll
            for (int r = 0; r < 4; ++r) {
                const int offa = g * 512 + r * 128 + ty * 8;
                const int offb = g * 512 + r * 128 + tx * 8;
                h4 vA = *(const h4*)(lds0 + offa);
                h4 vB = *(const h4*)(lds1 + offa);
                h4 vC = *(const h4*)(lds2 + offb);
                h4 vD = *(const h4*)(lds3 + offb);
                aIl[r] = __builtin_shufflevector(vA, vA, 0, 1); aIh[r] = __builtin_shufflevector(vA, vA, 2, 3);
                bIl[r] = __builtin_shufflevector(vB, vB, 0, 1); bIh[r] = __builtin_shufflevector(vB, vB, 2, 3);
                aJl[r] = __builtin_shufflevector(vC, vC, 0, 1); aJh[r] = __builtin_shufflevector(vC, vC, 2, 3);
                bJl[r] = __builtin_shufflevector(vD, vD, 0, 1); bJh[r] = __builtin_shufflevector(vD, vD, 2, 3);
            }
#pragma unroll
            for (int r = 0; r < 4; ++r)
#pragma unroll
                for (int c = 0; c < 4; ++c) {
                    cIJ[r][c] = fdot2(aIl[r], bJl[c], cIJ[r][c]);
                    cIJ[r][c] = fdot2(aIh[r], bJh[c], cIJ[r][c]);
                    cJI[r][c] = fdot2(bIl[r], aJl[c], cJI[r][c]);
                    cJI[r][c] = fdot2(bIh[r], aJh[c], cJI[r][c]);
                }
        }
    }

    // combine the two k-halves (before the nonlinearity)
    __syncthreads();
    float* sf = (float*)lds;
    if (h == 1) {
#pragma unroll
        for (int r = 0; r < 4; ++r)
#pragma unroll
            for (int c = 0; c < 4; ++c) {
                sf[(r * 4 + c) * 256 + t8]      = cIJ[r][c];
                sf[(16 + r * 4 + c) * 256 + t8] = cJI[r][c];
            }
    }
    __syncthreads();
    float ssum = 0.f;
    if (h == 0) {
#pragma unroll
        for (int r = 0; r < 4; ++r)
#pragma unroll
            for (int c = 0; c < 4; ++c) {
                float vij = cIJ[r][c] + sf[(r * 4 + c) * 256 + t8];
                float vji = cJI[r][c] + sf[(16 + r * 4 + c) * 256 + t8];
                float v = vij + vji - 1.f;
                if (v > 0.f) ssum += v * v;
            }
        ssum *= wgt;
    }
    ssum = wsum(ssum);
    __shared__ float red[8];
    if ((tid & 63) == 0) red[tid >> 6] = ssum;
    __syncthreads();
    if (tid == 0) {
        float d = 0.f;
#pragma unroll
        for (int i = 0; i < 8; ++i) d += red[i];
        dpart[b * 10 + p] = d;
    }
}

// ---- fused final reduction: part[4096][8] + dpart[640] -> out ----
__global__ __launch_bounds__(256) void final_kernel(const float* __restrict__ part,
                                                    const float* __restrict__ dpart,
                                                    float* __restrict__ out)
{
    const int t = threadIdx.x;
    const int b = t >> 2, qt = t & 3;
    float v[8] = {0,0,0,0,0,0,0,0};
    for (int i = 0; i < 16; ++i) {
        const float* pp = part + ((size_t)(b * 64 + qt * 16 + i)) * 8;
        float4 x = *(const float4*)pp;
        float4 y = *(const float4*)(pp + 4);
        v[0] += x.x; v[1] += x.y; v[2] += x.z; v[3] += x.w;
        v[4] += y.x; v[5] += y.y; v[6] += y.z; v[7] += y.w;
    }
#pragma unroll
    for (int k = 0; k < 8; ++k) {
        v[k] += __shfl_xor(v[k], 1);
        v[k] += __shfl_xor(v[k], 2);
    }
    float m = (qt == 0) ? 1.f : 0.f;
    float r0 = m * v[0], r1 = m * v[1], r2 = m * v[2], r3 = m * v[3];
    float r4 = m * v[4], r5 = m * v[5];
    float ge = m * (__expf(-v[6]) + __expf(-v[7]));
    float d = 0.f;
    for (int i = t; i < 640; i += 256) d += dpart[i];

    r0 = wsum(r0); r1 = wsum(r1); r2 = wsum(r2); r3 = wsum(r3);
    r4 = wsum(r4); r5 = wsum(r5); ge = wsum(ge); d = wsum(d);
    __shared__ float red[4][8];
    const int w = t >> 6;
    if ((t & 63) == 0) {
        red[w][0] = r0; red[w][1] = r1; red[w][2] = r2; red[w][3] = r3;
        red[w][4] = r4; red[w][5] = r5; red[w][6] = ge; red[w][7] = d;
    }
    __syncthreads();
    if (t == 0) {
        float s[8];
#pragma unroll
        for (int k = 0; k < 8; ++k)
            s[k] = red[0][k] + red[1][k] + red[2][k] + red[3][k];
        float denom = s[1] + 1e-8f;
        float type_loss = s[0] / 65536.f;
        float node = 0.5f * (s[2] / denom + s[3] / denom);
        float value = s[4] / denom;
        float self = s[5] / denom;
        float g = s[6] * (1.f / 64.f);
        float dup = s[7] / (64.f * 256.f * 256.f);
        out[0] = 1.0f * type_loss + 0.5f * node + 1.0f * value
               + 2.0f * self + 1.0f * dup + 0.5f * g;
    }
}

extern "C" void kernel_launch(void* const* d_in, const int* in_sizes, int n_in,
                              void* d_out, int out_size, void* d_ws, size_t ws_size,
                              hipStream_t stream)
{
    const float* tl   = (const float*)d_in[0];
    const float* al   = (const float*)d_in[1];
    const float* bl   = (const float*)d_in[2];
    const float* vals = (const float*)d_in[3];
    const float* seq  = (const float*)d_in[4];

    char* ws = (char*)d_ws;
    int*   cnt     = (int*)ws;
    int*   skip    = (int*)(ws + SKIP_OFF);
    short* slotmap = (short*)(ws + SLOT_OFF);
    float* part    = (float*)(ws + PART_OFF);
    float* dpart   = (float*)(ws + DPART_OFF);
    unsigned short* ma = (unsigned short*)(ws + MA_OFF);
    unsigned short* pb = (unsigned short*)(ws + PB_OFF);

    scan_kernel<<<64, 256, 0, stream>>>(seq, cnt, slotmap);
    stats_kernel<<<4096, 256, 0, stream>>>(tl, al, bl, vals, seq, slotmap,
                                           part, ma, pb);
    norm_kernel<<<64, 1024, 0, stream>>>(ma, pb, cnt, skip);
    dim3 gg(10, 64);
    gemm_dup<<<gg, 512, 0, stream>>>(ma, pb, cnt, skip, dpart);
    final_kernel<<<1, 256, 0, stream>>>(part, dpart, (float*)d_out);
}

// Round 16
// 52.370 us; speedup vs baseline: 1.6264x; 1.1505x over previous
//
#include <hip/hip_runtime.h>
#include <hip/hip_bf16.h>
#include <math.h>

#define TT 1024
#define NTYPE 16
#define NNODE 256
#define KCAP 512   // compacted masked rows per batch (expected ~192; 26 sigma headroom)

// ws layout (bytes):
//   0        : cnt[64] int
//   1024     : slotmap[64][1024] short          128 KB
//   132096   : part[4096][8] f32                128 KB
//   265216   : dpart[64][10] f32                2.5 KB
//   270336   : nrm[64][8][2] f32                4 KB  (per batch,chunk column-norm maxes)
//   1048576  : ma [64][KCAP][256] f16           16 MB
//   +16M     : pb [64][KCAP][256] f16           16 MB
#define SLOT_OFF  1024
#define PART_OFF  132096
#define DPART_OFF 265216
#define NRM_OFF   270336
#define MA_OFF    1048576ll
#define PB_OFF    (MA_OFF + 64ll*KCAP*256*2)

typedef __fp16 h2 __attribute__((ext_vector_type(2)));
typedef __fp16 h4 __attribute__((ext_vector_type(4)));
typedef float  f4v __attribute__((ext_vector_type(4)));

__device__ __forceinline__ float wsum(float v) {
    for (int o = 32; o > 0; o >>= 1) v += __shfl_xor(v, o);
    return v;
}
// DPP butterfly adds (VALU pipe, no LDS)
template<int CTRL>
__device__ __forceinline__ float dppadd(float v) {
    int p = __builtin_amdgcn_update_dpp(0, __float_as_int(v), CTRL, 0xF, 0xF, true);
    return v + __int_as_float(p);
}
__device__ __forceinline__ float gsum16(float v) {
    v = dppadd<0xB1>(v);    // quad_perm [1,0,3,2]
    v = dppadd<0x4E>(v);    // quad_perm [2,3,0,1]
    v = dppadd<0x141>(v);   // row_half_mirror
    v = dppadd<0x140>(v);   // row_mirror
    return v;
}
__device__ __forceinline__ unsigned pkh(float x, float y) {  // pack 2 f32 -> 2 f16
    h2 r = __builtin_amdgcn_cvt_pkrtz(x, y);
    union { h2 h; unsigned u; } c; c.h = r; return c.u;
}
__device__ __forceinline__ float fdot2(h2 a, h2 b, float c) {
#if __has_builtin(__builtin_amdgcn_fdot2)
    return __builtin_amdgcn_fdot2(a, b, c, false);
#else
    return c + (float)a[0] * (float)b[0] + (float)a[1] * (float)b[1];
#endif
}
__device__ __forceinline__ float4 ntload4(const float* p) {
    f4v v = __builtin_nontemporal_load((const f4v*)p);
    return make_float4(v.x, v.y, v.z, v.w);
}
__device__ __forceinline__ float sel4(float4 v, int e) {
    float x = (e & 1) ? v.y : v.x;
    float y = (e & 1) ? v.w : v.z;
    return (e & 2) ? y : x;
}
__device__ __forceinline__ float sel16(float4 v0, float4 v1, float4 v2, float4 v3,
                                       int j, int e) {
    float s0 = sel4(v0, e), s1 = sel4(v1, e), s2 = sel4(v2, e), s3 = sel4(v3, e);
    float c01 = (j & 1) ? s1 : s0;
    float c23 = (j & 1) ? s3 : s2;
    return (j & 2) ? c23 : c01;
}

// ---- deterministic compaction slots: per-batch prefix sum of the mask ----
__global__ __launch_bounds__(256) void scan_kernel(const float* __restrict__ seq,
                                                   int* __restrict__ cnt,
                                                   short* __restrict__ slotmap)
{
    const int b = blockIdx.x;
    const int tid = threadIdx.x;
    const int lane = tid & 63, w = tid >> 6;
    const int t0 = tid * 4;
    int m0 = 0, m1 = 0, m2 = 0, m3 = 0;
    {
        int tt;
        tt = (int)seq[((size_t)b * TT + t0 + 1) * 4];               m0 = (tt >= 3 && tt <= 5);
        tt = (int)seq[((size_t)b * TT + t0 + 2) * 4];               m1 = (tt >= 3 && tt <= 5);
        tt = (int)seq[((size_t)b * TT + t0 + 3) * 4];               m2 = (tt >= 3 && tt <= 5);
        if (t0 + 3 < TT - 1) {
            tt = (int)seq[((size_t)b * TT + t0 + 4) * 4];           m3 = (tt >= 3 && tt <= 5);
        }
    }
    int lc = m0 + m1 + m2 + m3;
    int inc = lc;
    for (int o = 1; o < 64; o <<= 1) {
        int v = __shfl_up(inc, o);
        if (lane >= o) inc += v;
    }
    __shared__ int wtot[4];
    if (lane == 63) wtot[w] = inc;
    __syncthreads();
    int woff = 0;
    for (int i = 0; i < 4; ++i) woff += (i < w) ? wtot[i] : 0;
    int run = woff + inc - lc;
    if (m0) { slotmap[(size_t)b * TT + t0 + 0] = (short)run; ++run; }
    if (m1) { slotmap[(size_t)b * TT + t0 + 1] = (short)run; ++run; }
    if (m2) { slotmap[(size_t)b * TT + t0 + 2] = (short)run; ++run; }
    if (m3) { slotmap[(size_t)b * TT + t0 + 3] = (short)run; ++run; }
    if (tid == 255) cnt[b] = woff + inc;
}

// ---- fused per-row stats: 16-lane group per row, 4 rows per wave ----
__global__ __launch_bounds__(256) void stats_kernel(
    const float* __restrict__ tl, const float* __restrict__ al,
    const float* __restrict__ bl, const float* __restrict__ vals,
    const float* __restrict__ seq, const short* __restrict__ slotmap,
    float* __restrict__ part,
    unsigned short* __restrict__ ma, unsigned short* __restrict__ pb)
{
    const int tid = threadIdx.x;
    const int w = tid >> 6, lane = tid & 63;
    const int s = lane & 15;                       // sublane within 16-lane group
    const int rowbase = blockIdx.x * 16 + w * 4;
    const int row = rowbase + (lane >> 4);
    const int b = row >> 10, t = row & 1023;

    // shifted target (group-uniform)
    float4 tgt = make_float4(0.f, 0.f, 0.f, 0.f);
    if (t < TT - 1) tgt = *(const float4*)(seq + (size_t)(row + 1) * 4);
    const int   t_type = (int)tgt.x;
    const int   t_a    = (int)tgt.y;
    const int   t_b    = (int)tgt.z;
    const float t_val  = tgt.w;
    const float mask   = (t_type >= 3 && t_type <= 5) ? 1.f : 0.f;

    // ---- type softmax: exactly 1 logit per sublane ----
    float tlv = tl[(size_t)rowbase * 16 + lane];
    float te  = __expf(tlv);
    float tsum = gsum16(te);
    float tcs  = gsum16((s >= 3 && s <= 5) ? te : 0.f);
    float p_comp = tcs / tsum;
    float ce_type = __logf(tsum) - __shfl(tlv, (lane & 48) + t_type);

    // ---- node a/b: 16 logits per sublane (4 x float4, stride-64 chunks) ----
    const float* arow = al + (size_t)row * 256;
    float4 a0 = ntload4(arow + s * 4);
    float4 a1 = ntload4(arow + s * 4 + 64);
    float4 a2 = ntload4(arow + s * 4 + 128);
    float4 a3 = ntload4(arow + s * 4 + 192);
    const float* brow = bl + (size_t)row * 256;
    float4 b0 = ntload4(brow + s * 4);
    float4 b1 = ntload4(brow + s * 4 + 64);
    float4 b2 = ntload4(brow + s * 4 + 128);
    float4 b3 = ntload4(brow + s * 4 + 192);

    // CE gathers on raw logits
    const int ja = t_a >> 6, sa = (t_a >> 2) & 15, ea = t_a & 3;
    const int jb = t_b >> 6, sb = (t_b >> 2) & 15, eb = t_b & 3;
    float ga = __shfl(sel16(a0, a1, a2, a3, ja, ea), (lane & 48) + sa);
    float gb = __shfl(sel16(b0, b1, b2, b3, jb, eb), (lane & 48) + sb);

    float ea0x = __expf(a0.x), ea0y = __expf(a0.y), ea0z = __expf(a0.z), ea0w = __expf(a0.w);
    float ea1x = __expf(a1.x), ea1y = __expf(a1.y), ea1z = __expf(a1.z), ea1w = __expf(a1.w);
    float ea2x = __expf(a2.x), ea2y = __expf(a2.y), ea2z = __expf(a2.z), ea2w = __expf(a2.w);
    float ea3x = __expf(a3.x), ea3y = __expf(a3.y), ea3z = __expf(a3.z), ea3w = __expf(a3.w);
    float eb0x = __expf(b0.x), eb0y = __expf(b0.y), eb0z = __expf(b0.z), eb0w = __expf(b0.w);
    float eb1x = __expf(b1.x), eb1y = __expf(b1.y), eb1z = __expf(b1.z), eb1w = __expf(b1.w);
    float eb2x = __expf(b2.x), eb2y = __expf(b2.y), eb2z = __expf(b2.z), eb2w = __expf(b2.w);
    float eb3x = __expf(b3.x), eb3y = __expf(b3.y), eb3z = __expf(b3.z), eb3w = __expf(b3.w);

    float lsa = ((ea0x + ea0y) + (ea0z + ea0w)) + ((ea1x + ea1y) + (ea1z + ea1w))
              + ((ea2x + ea2y) + (ea2z + ea2w)) + ((ea3x + ea3y) + (ea3z + ea3w));
    float lsb = ((eb0x + eb0y) + (eb0z + eb0w)) + ((eb1x + eb1y) + (eb1z + eb1w))
              + ((eb2x + eb2y) + (eb2z + eb2w)) + ((eb3x + eb3y) + (eb3z + eb3w));
    float asum = gsum16(lsa);
    float bsum = gsum16(lsb);
    float ainv = 1.f / asum, binv = 1.f / bsum;

    float ce_a = __logf(asum) - ga;
    float ce_b = __logf(bsum) - gb;

    // selfloop dot
    float dl = ((ea0x * eb0x + ea0y * eb0y) + (ea0z * eb0z + ea0w * eb0w))
             + ((ea1x * eb1x + ea1y * eb1y) + (ea1z * eb1z + ea1w * eb1w))
             + ((ea2x * eb2x + ea2y * eb2y) + (ea2z * eb2z + ea2w * eb2w))
             + ((ea3x * eb3x + ea3y * eb3y) + (ea3z * eb3z + ea3w * eb3w));
    float dot = gsum16(dl) * ainv * binv;

    // gnd: node cols 0,1 live on sublane 0 elements x,y
    float s0c = ((ea0x * ainv) + (eb0x * binv)) * p_comp;
    float s1c = ((ea0y * ainv) + (eb0y * binv)) * p_comp;

    float pv = vals[row];
    float vloss = mask * (pv - t_val) * (pv - t_val);

    // ---- compacted f16 prob rows ----
    if (mask > 0.f) {
        int slot = slotmap[row];
        if (slot < KCAP) {
            size_t base = ((size_t)b * KCAP + slot) * 256 + s * 4;
            *(uint2*)(ma + base)       = make_uint2(pkh(ea0x * ainv, ea0y * ainv), pkh(ea0z * ainv, ea0w * ainv));
            *(uint2*)(ma + base + 64)  = make_uint2(pkh(ea1x * ainv, ea1y * ainv), pkh(ea1z * ainv, ea1w * ainv));
            *(uint2*)(ma + base + 128) = make_uint2(pkh(ea2x * ainv, ea2y * ainv), pkh(ea2z * ainv, ea2w * ainv));
            *(uint2*)(ma + base + 192) = make_uint2(pkh(ea3x * ainv, ea3y * ainv), pkh(ea3z * ainv, ea3w * ainv));
            *(uint2*)(pb + base)       = make_uint2(pkh(eb0x * binv, eb0y * binv), pkh(eb0z * binv, eb0w * binv));
            *(uint2*)(pb + base + 64)  = make_uint2(pkh(eb1x * binv, eb1y * binv), pkh(eb1z * binv, eb1w * binv));
            *(uint2*)(pb + base + 128) = make_uint2(pkh(eb2x * binv, eb2y * binv), pkh(eb2z * binv, eb2w * binv));
            *(uint2*)(pb + base + 192) = make_uint2(pkh(eb3x * binv, eb3y * binv), pkh(eb3z * binv, eb3w * binv));
        }
    }

    // ---- reduce 8 scalars: group leaders, then xor16+xor32 across groups ----
    float r0 = (s == 0) ? ce_type       : 0.f;
    float r1 = (s == 0) ? mask          : 0.f;
    float r2 = (s == 0) ? mask * ce_a   : 0.f;
    float r3 = (s == 0) ? mask * ce_b   : 0.f;
    float r4 = (s == 0) ? vloss         : 0.f;
    float r5 = (s == 0) ? mask * dot    : 0.f;
    float r6 = (s == 0) ? s0c           : 0.f;
    float r7 = (s == 0) ? s1c           : 0.f;
#define XR(v) v += __shfl_xor(v, 16); v += __shfl_xor(v, 32);
    XR(r0) XR(r1) XR(r2) XR(r3) XR(r4) XR(r5) XR(r6) XR(r7)
#undef XR
    __shared__ float red[4][8];
    if (lane == 0) {
        red[w][0] = r0; red[w][1] = r1; red[w][2] = r2; red[w][3] = r3;
        red[w][4] = r4; red[w][5] = r5; red[w][6] = r6; red[w][7] = r7;
    }
    __syncthreads();
    if (tid < 8) {
        part[(size_t)blockIdx.x * 8 + tid] =
            red[0][tid] + red[1][tid] + red[2][tid] + red[3][tid];
    }
}

// ---- per-(batch,chunk) column-norm partial maxes (Cauchy-Schwarz inputs) ----
// 512 blocks = 64 batches x 8 col-chunks of 32 cols; 256 threads.
// Thread (ct,kt): cols {ch*32+ct*2, +1}, rows k = kt, kt+16, ... (dword loads).
// Writes nrm[b][ch] = {max_i ||ma_col||^2, max_j ||pb_col||^2} over its 32 cols.
__global__ __launch_bounds__(256) void norm_kernel(
    const unsigned short* __restrict__ ma, const unsigned short* __restrict__ pb,
    const int* __restrict__ cnt, float* __restrict__ nrm)
{
    const int b = blockIdx.x >> 3, ch = blockIdx.x & 7;
    int K = cnt[b]; if (K > KCAP) K = KCAP;
    const int t = threadIdx.x;
    const int lane = t & 63, w = t >> 6;
    const int ct = t & 15;
    const int kt = t >> 4;          // 0..15
    const unsigned short* pA = ma + (size_t)b * KCAP * 256 + ch * 32 + ct * 2;
    const unsigned short* pB = pb + (size_t)b * KCAP * 256 + ch * 32 + ct * 2;
    float a0s = 0.f, a1s = 0.f, b0s = 0.f, b1s = 0.f;
    for (int k = kt; k < K; k += 16) {
        unsigned ua = *(const unsigned*)(pA + (size_t)k * 256);
        unsigned ub = *(const unsigned*)(pB + (size_t)k * 256);
        union { unsigned u; h2 h; } ca, cb; ca.u = ua; cb.u = ub;
        float a0 = (float)ca.h[0], a1 = (float)ca.h[1];
        float b0 = (float)cb.h[0], b1 = (float)cb.h[1];
        a0s += a0 * a0; a1s += a1 * a1;
        b0s += b0 * b0; b1s += b1 * b1;
    }
    // reduce over the wave's 4 kt values (lane>>4): xor 16, 32
#define KR(v) v += __shfl_xor(v, 16); v += __shfl_xor(v, 32);
    KR(a0s) KR(a1s) KR(b0s) KR(b1s)
#undef KR
    __shared__ float red[4][16][4];
    if (lane < 16) {
        red[w][lane][0] = a0s; red[w][lane][1] = a1s;
        red[w][lane][2] = b0s; red[w][lane][3] = b1s;
    }
    __syncthreads();
    if (t < 16) {
        float A0 = 0.f, A1 = 0.f, B0 = 0.f, B1 = 0.f;
#pragma unroll
        for (int ww = 0; ww < 4; ++ww) {
            A0 += red[ww][t][0]; A1 += red[ww][t][1];
            B0 += red[ww][t][2]; B1 += red[ww][t][3];
        }
        float Am = fmaxf(A0, A1), Bm = fmaxf(B0, B1);
        for (int o = 1; o < 16; o <<= 1) {
            Am = fmaxf(Am, __shfl_xor(Am, o));
            Bm = fmaxf(Bm, __shfl_xor(Bm, o));
        }
        if (t == 0) {
            nrm[(b * 8 + ch) * 2]     = Am;
            nrm[(b * 8 + ch) * 2 + 1] = Bm;
        }
    }
}

// ---- fused ec GEMM + dup penalty (fallback path; early-exits when bound holds) ----
// ec[i][j] <= ||ma_col_i||*||pb_col_j||; if 4*maxA2*maxB2 < 0.25 (safety 2x over
// the needed <=1), every ec_sym entry < 1 and relu(ec_sym-1)^2 == 0 EXACTLY.
__constant__ int cTI[10] = {0, 1, 2, 3, 0, 0, 0, 1, 1, 2};
__constant__ int cTJ[10] = {0, 1, 2, 3, 1, 2, 3, 2, 3, 3};

__global__ __launch_bounds__(512) void gemm_dup(
    const unsigned short* __restrict__ ma, const unsigned short* __restrict__ pb,
    const int* __restrict__ cnt, const float* __restrict__ nrm,
    float* __restrict__ dpart)
{
    const int b = blockIdx.y;
    const int p = blockIdx.x;
    {
        const float* nb = nrm + b * 16;
        float MA = 0.f, MB = 0.f;
#pragma unroll
        for (int i = 0; i < 8; ++i) {
            MA = fmaxf(MA, nb[i * 2]);
            MB = fmaxf(MB, nb[i * 2 + 1]);
        }
        if (4.f * MA * MB < 0.25f) {        // dup contribution provably zero
            if (threadIdx.x == 0) dpart[b * 10 + p] = 0.f;
            return;
        }
    }
    __shared__ __align__(16) char lds[32768];
    char* lds0 = lds;
    char* lds1 = lds + 8192;
    char* lds2 = lds + 16384;
    char* lds3 = lds + 24576;
    int K = cnt[b]; if (K > KCAP) K = KCAP;
    const int I0 = cTI[p] * 64, J0 = cTJ[p] * 64;
    const float wgt = (I0 == J0) ? 1.f : 2.f;
    const int tid = threadIdx.x;
    const int lr = tid >> 3, lc = (tid & 7) * 8;   // staging: 64 k-rows x 64 cols
    const int h  = tid >> 8;                       // k-half for compute
    const int t8 = tid & 255;
    const int tx = t8 & 15, ty = t8 >> 4;
    const size_t bb = (size_t)b * KCAP * 256;
    float cIJ[4][4] = {};
    float cJI[4][4] = {};

    for (int k0 = 0; k0 < K; k0 += 64) {
        const int kr = k0 + lr;
        uint4 vai = make_uint4(0,0,0,0), vbi = vai, vaj = vai, vbj = vai;
        if (kr < K) {
            size_t rb = bb + (size_t)kr * 256;
            vai = *(const uint4*)(ma + rb + I0 + lc);
            vbi = *(const uint4*)(pb + rb + I0 + lc);
            vaj = *(const uint4*)(ma + rb + J0 + lc);
            vbj = *(const uint4*)(pb + rb + J0 + lc);
        }
        __syncthreads();
        {
            const int g = lr >> 2;
            const int ko = (lr & 3) * 2;
            const __fp16* hai = (const __fp16*)&vai;
            const __fp16* hbi = (const __fp16*)&vbi;
            const __fp16* haj = (const __fp16*)&vaj;
            const __fp16* hbj = (const __fp16*)&vbj;
#pragma unroll
            for (int j = 0; j < 8; ++j) {
                const int cg = (tid & 7) * 2 + (j >> 2);
                const int off = g * 512 + (j & 3) * 128 + cg * 8 + ko;
                *(__fp16*)(lds0 + off) = hai[j];
                *(__fp16*)(lds1 + off) = hbi[j];
                *(__fp16*)(lds2 + off) = haj[j];
                *(__fp16*)(lds3 + off) = hbj[j];
            }
        }
        __syncthreads();
#pragma unroll
        for (int gg = 0; gg < 8; ++gg) {
            const int g = h * 8 + gg;
            h2 aIl[4], aIh[4], bIl[4], bIh[4], aJl[4], aJh[4], bJl[4], bJh[4];
#pragma unroll
            for (int r = 0; r < 4; ++r) {
                const int offa = g * 512 + r * 128 + ty * 8;
                const int offb = g * 512 + r * 128 + tx * 8;
                h4 vA = *(const h4*)(lds0 + offa);
                h4 vB = *(const h4*)(lds1 + offa);
                h4 vC = *(const h4*)(lds2 + offb);
                h4 vD = *(const h4*)(lds3 + offb);
                aIl[r] = __builtin_shufflevector(vA, vA, 0, 1); aIh[r] = __builtin_shufflevector(vA, vA, 2, 3);
                bIl[r] = __builtin_shufflevector(vB, vB, 0, 1); bIh[r] = __builtin_shufflevector(vB, vB, 2, 3);
                aJl[r] = __builtin_shufflevector(vC, vC, 0, 1); aJh[r] = __builtin_shufflevector(vC, vC, 2, 3);
                bJl[r] = __builtin_shufflevector(vD, vD, 0, 1); bJh[r] = __builtin_shufflevector(vD, vD, 2, 3);
            }
#pragma unroll
            for (int r = 0; r < 4; ++r)
#pragma unroll
                for (int c = 0; c < 4; ++c) {
                    cIJ[r][c] = fdot2(aIl[r], bJl[c], cIJ[r][c]);
                    cIJ[r][c] = fdot2(aIh[r], bJh[c], cIJ[r][c]);
                    cJI[r][c] = fdot2(bIl[r], aJl[c], cJI[r][c]);
                    cJI[r][c] = fdot2(bIh[r], aJh[c], cJI[r][c]);
                }
        }
    }

    // combine the two k-halves (before the nonlinearity)
    __syncthreads();
    float* sf = (float*)lds;
    if (h == 1) {
#pragma unroll
        for (int r = 0; r < 4; ++r)
#pragma unroll
            for (int c = 0; c < 4; ++c) {
                sf[(r * 4 + c) * 256 + t8]      = cIJ[r][c];
                sf[(16 + r * 4 + c) * 256 + t8] = cJI[r][c];
            }
    }
    __syncthreads();
    float ssum = 0.f;
    if (h == 0) {
#pragma unroll
        for (int r = 0; r < 4; ++r)
#pragma unroll
            for (int c = 0; c < 4; ++c) {
                float vij = cIJ[r][c] + sf[(r * 4 + c) * 256 + t8];
                float vji = cJI[r][c] + sf[(16 + r * 4 + c) * 256 + t8];
                float v = vij + vji - 1.f;
                if (v > 0.f) ssum += v * v;
            }
        ssum *= wgt;
    }
    ssum = wsum(ssum);
    __shared__ float red[8];
    if ((tid & 63) == 0) red[tid >> 6] = ssum;
    __syncthreads();
    if (tid == 0) {
        float d = 0.f;
#pragma unroll
        for (int i = 0; i < 8; ++i) d += red[i];
        dpart[b * 10 + p] = d;
    }
}

// ---- fused final reduction: part[4096][8] + dpart[640] -> out ----
__global__ __launch_bounds__(256) void final_kernel(const float* __restrict__ part,
                                                    const float* __restrict__ dpart,
                                                    float* __restrict__ out)
{
    const int t = threadIdx.x;
    const int b = t >> 2, qt = t & 3;
    float v[8] = {0,0,0,0,0,0,0,0};
    for (int i = 0; i < 16; ++i) {
        const float* pp = part + ((size_t)(b * 64 + qt * 16 + i)) * 8;
        float4 x = *(const float4*)pp;
        float4 y = *(const float4*)(pp + 4);
        v[0] += x.x; v[1] += x.y; v[2] += x.z; v[3] += x.w;
        v[4] += y.x; v[5] += y.y; v[6] += y.z; v[7] += y.w;
    }
#pragma unroll
    for (int k = 0; k < 8; ++k) {
        v[k] += __shfl_xor(v[k], 1);
        v[k] += __shfl_xor(v[k], 2);
    }
    float m = (qt == 0) ? 1.f : 0.f;
    float r0 = m * v[0], r1 = m * v[1], r2 = m * v[2], r3 = m * v[3];
    float r4 = m * v[4], r5 = m * v[5];
    float ge = m * (__expf(-v[6]) + __expf(-v[7]));
    float d = 0.f;
    for (int i = t; i < 640; i += 256) d += dpart[i];

    r0 = wsum(r0); r1 = wsum(r1); r2 = wsum(r2); r3 = wsum(r3);
    r4 = wsum(r4); r5 = wsum(r5); ge = wsum(ge); d = wsum(d);
    __shared__ float red[4][8];
    const int w = t >> 6;
    if ((t & 63) == 0) {
        red[w][0] = r0; red[w][1] = r1; red[w][2] = r2; red[w][3] = r3;
        red[w][4] = r4; red[w][5] = r5; red[w][6] = ge; red[w][7] = d;
    }
    __syncthreads();
    if (t == 0) {
        float s[8];
#pragma unroll
        for (int k = 0; k < 8; ++k)
            s[k] = red[0][k] + red[1][k] + red[2][k] + red[3][k];
        float denom = s[1] + 1e-8f;
        float type_loss = s[0] / 65536.f;
        float node = 0.5f * (s[2] / denom + s[3] / denom);
        float value = s[4] / denom;
        float self = s[5] / denom;
        float g = s[6] * (1.f / 64.f);
        float dup = s[7] / (64.f * 256.f * 256.f);
        out[0] = 1.0f * type_loss + 0.5f * node + 1.0f * value
               + 2.0f * self + 1.0f * dup + 0.5f * g;
    }
}

extern "C" void kernel_launch(void* const* d_in, const int* in_sizes, int n_in,
                              void* d_out, int out_size, void* d_ws, size_t ws_size,
                              hipStream_t stream)
{
    const float* tl   = (const float*)d_in[0];
    const float* al   = (const float*)d_in[1];
    const float* bl   = (const float*)d_in[2];
    const float* vals = (const float*)d_in[3];
    const float* seq  = (const float*)d_in[4];

    char* ws = (char*)d_ws;
    int*   cnt     = (int*)ws;
    short* slotmap = (short*)(ws + SLOT_OFF);
    float* part    = (float*)(ws + PART_OFF);
    float* dpart   = (float*)(ws + DPART_OFF);
    float* nrm     = (float*)(ws + NRM_OFF);
    unsigned short* ma = (unsigned short*)(ws + MA_OFF);
    unsigned short* pb = (unsigned short*)(ws + PB_OFF);

    scan_kernel<<<64, 256, 0, stream>>>(seq, cnt, slotmap);
    stats_kernel<<<4096, 256, 0, stream>>>(tl, al, bl, vals, seq, slotmap,
                                           part, ma, pb);
    norm_kernel<<<512, 256, 0, stream>>>(ma, pb, cnt, nrm);
    dim3 gg(10, 64);
    gemm_dup<<<gg, 512, 0, stream>>>(ma, pb, cnt, nrm, dpart);
    final_kernel<<<1, 256, 0, stream>>>(part, dpart, (float*)d_out);
}